// Round 1
// baseline (717.165 us; speedup 1.0000x reference)
//
#include <hip/hip_runtime.h>

typedef short bf16x8 __attribute__((ext_vector_type(8)));
typedef float f32x4 __attribute__((ext_vector_type(4)));

#define MFMA16(a, b, c) __builtin_amdgcn_mfma_f32_16x16x32_bf16((a), (b), (c), 0, 0, 0)

#define SEQ 4096
#define CD 512

__device__ __forceinline__ unsigned short f2bf(float f) {
  unsigned u = __builtin_bit_cast(unsigned, f);
  u = u + 0x7FFFu + ((u >> 16) & 1u);
  return (unsigned short)(u >> 16);
}

__device__ __forceinline__ void gload_lds16(const void* g, void* l) {
  __builtin_amdgcn_global_load_lds(
      (const __attribute__((address_space(1))) void*)g,
      (__attribute__((address_space(3))) void*)l, 16, 0, 0);
}

// ---------------- weight convert (fp32 -> bf16, fold softmax scale into Wq/bq) ----------------
__global__ __launch_bounds__(256) void convert_w(
    const float* __restrict__ Wq, const float* __restrict__ Wk,
    const float* __restrict__ Wv, const float* __restrict__ Wo,
    const float* __restrict__ bq, const float* __restrict__ bk,
    const float* __restrict__ bv, const float* __restrict__ bo,
    unsigned short* __restrict__ W4, float* __restrict__ b4) {
  int i = blockIdx.x * 256 + threadIdx.x;            // 4*512*512 total
  int p = i >> 18, idx = i & 262143;
  const float sc = 1.4426950408889634f * 0.04419417382415922f;  // log2(e) * 512^-0.5
  const float* W = (p == 0) ? Wq : (p == 1) ? Wk : (p == 2) ? Wv : Wo;
  float v = W[idx] * ((p == 0) ? sc : 1.0f);
  W4[i] = f2bf(v);
  if (idx < 512) {
    const float* bb = (p == 0) ? bq : (p == 1) ? bk : (p == 2) ? bv : bo;
    b4[(p << 9) + idx] = bb[idx] * ((p == 0) ? sc : 1.0f);
  }
}

// ---------------- transpose q: fp32 [b][c][s] -> bf16 qT [b][s][c] ----------------
__global__ __launch_bounds__(256) void transpose_q(
    const float* __restrict__ q, unsigned short* __restrict__ qT) {
  __shared__ float tile[32][33];
  const int b = blockIdx.z, c0 = blockIdx.y * 32, s0 = blockIdx.x * 32;
  const int tx = threadIdx.x & 31, ty = threadIdx.x >> 5;
  #pragma unroll
  for (int i = 0; i < 4; i++) {
    int c = ty + i * 8;
    tile[c][tx] = q[((size_t)b * CD + c0 + c) * SEQ + s0 + tx];
  }
  __syncthreads();
  #pragma unroll
  for (int i = 0; i < 4; i++) {
    int s = ty + i * 8;
    qT[((size_t)b * SEQ + s0 + s) * CD + c0 + tx] = f2bf(tile[tx][s]);
  }
}

// ---------------- shared BT-GEMM core: 128x128 tile, BK=64, 4 waves ----------------
// A [.][512] bf16 row-major (rows m0..m0+127 passed via Ap), Bt likewise.
// LDS chunks source-swizzled: slot (row, kc) holds global chunk (kc ^ (row&7)).
__device__ __forceinline__ void gemm_core(
    const unsigned short* __restrict__ Ap, const unsigned short* __restrict__ Bp,
    unsigned short* As, unsigned short* Bs, f32x4 acc[4][4]) {
  const int t = threadIdx.x;
  const int wid = t >> 6, lane = t & 63;
  const int l15 = lane & 15, l4 = lane >> 4;
  const int wr = wid >> 1, wc = wid & 1;
  for (int k0 = 0; k0 < 512; k0 += 64) {
    #pragma unroll
    for (int j = 0; j < 4; j++) {
      int slot = j * 256 + t;
      int row = slot >> 3, kc = slot & 7;
      int kcs = kc ^ (row & 7);
      gload_lds16(Ap + (size_t)row * 512 + k0 + kcs * 8, As + (j * 256 + wid * 64) * 8);
      gload_lds16(Bp + (size_t)row * 512 + k0 + kcs * 8, Bs + (j * 256 + wid * 64) * 8);
    }
    __syncthreads();
    #pragma unroll
    for (int ks = 0; ks < 2; ks++) {
      bf16x8 af[4], bf[4];
      #pragma unroll
      for (int i = 0; i < 4; i++) {
        int ra = wr * 64 + i * 16 + l15;
        af[i] = *(const bf16x8*)(As + ra * 64 + (((ks << 2) | l4) ^ (ra & 7)) * 8);
        int rb = wc * 64 + i * 16 + l15;
        bf[i] = *(const bf16x8*)(Bs + rb * 64 + (((ks << 2) | l4) ^ (rb & 7)) * 8);
      }
      #pragma unroll
      for (int i = 0; i < 4; i++)
        #pragma unroll
        for (int j = 0; j < 4; j++)
          acc[i][j] = MFMA16(af[i], bf[j], acc[i][j]);
    }
    __syncthreads();
  }
}

// ---------------- QKV projection: z = 0(Q),1(K),2(V transposed) ----------------
__global__ __launch_bounds__(256) void gemm_proj(
    const unsigned short* __restrict__ qT, const unsigned short* __restrict__ W4,
    const float* __restrict__ b4,
    unsigned short* __restrict__ Qf, unsigned short* __restrict__ Kf,
    unsigned short* __restrict__ VfT) {
  __shared__ unsigned short As[128 * 64], Bs[128 * 64];
  const int p = blockIdx.z;
  const int n0 = blockIdx.x * 128, m0 = blockIdx.y * 128;
  f32x4 acc[4][4];
  #pragma unroll
  for (int i = 0; i < 4; i++)
    #pragma unroll
    for (int j = 0; j < 4; j++) acc[i][j] = (f32x4){0.f, 0.f, 0.f, 0.f};
  gemm_core(qT + (size_t)m0 * 512, W4 + ((size_t)p * 512 + n0) * 512, As, Bs, acc);

  const int t = threadIdx.x;
  const int wid = t >> 6, lane = t & 63;
  const int l15 = lane & 15, l4 = lane >> 4;
  const int wr = wid >> 1, wc = wid & 1;

  if (p < 2) {
    unsigned short* out = (p == 0) ? Qf : Kf;
    #pragma unroll
    for (int j = 0; j < 4; j++) {
      int n = n0 + wc * 64 + j * 16 + l15;
      float bias = b4[p * 512 + n];
      #pragma unroll
      for (int i = 0; i < 4; i++) {
        int m = m0 + wr * 64 + i * 16 + l4 * 4;
        #pragma unroll
        for (int r = 0; r < 4; r++)
          out[(size_t)(m + r) * 512 + n] = f2bf(acc[i][j][r] + bias);
      }
    }
  } else {
    int bb = m0 >> 12, sb = m0 & 4095;
    #pragma unroll
    for (int j = 0; j < 4; j++) {
      int n = n0 + wc * 64 + j * 16 + l15;
      float bias = b4[2 * 512 + n];
      #pragma unroll
      for (int i = 0; i < 4; i++) {
        int s = sb + wr * 64 + i * 16 + l4 * 4;
        ushort4 v;
        v.x = f2bf(acc[i][j][0] + bias);
        v.y = f2bf(acc[i][j][1] + bias);
        v.z = f2bf(acc[i][j][2] + bias);
        v.w = f2bf(acc[i][j][3] + bias);
        *(ushort4*)&VfT[((size_t)bb * CD + n) * SEQ + s] = v;
      }
    }
  }
}

// ---------------- flash attention: QBLK=64, KVBLK=64, 8 waves ----------------
__global__ __launch_bounds__(512) void flash_attn(
    const unsigned short* __restrict__ Qf, const unsigned short* __restrict__ Kf,
    const unsigned short* __restrict__ VfT, unsigned short* __restrict__ Ao) {
  __shared__ unsigned short Qs[64 * 512];   // 64KB, chunk-swizzled
  __shared__ unsigned short Ps[64 * 64];    // 8KB, [q][kv], byte-swizzled
  __shared__ float smx[2][4][32];
  __shared__ float ssm[2][4][32];

  const int t = threadIdx.x;
  const int wid = t >> 6, lane = t & 63;
  const int cw = wid & 3, qw = wid >> 2;
  const int l15 = lane & 15, l4 = lane >> 4;
  const int b = blockIdx.y;
  const int q0 = blockIdx.x * 64;

  {  // stage Q tile (64 x 512) into LDS, source-chunk swizzled
    const unsigned short* qb = Qf + ((size_t)b * SEQ + q0) * CD;
    #pragma unroll
    for (int i = 0; i < 8; i++) {
      int slot = i * 512 + t;
      int row = slot >> 6, kc = slot & 63;
      int kcs = kc ^ (row & 7);
      gload_lds16(qb + (size_t)row * CD + kcs * 8, Qs + (size_t)(i * 512 + wid * 64) * 8);
    }
  }
  __syncthreads();

  const int jq[2] = {qw * 32 + l15, qw * 32 + 16 + l15};
  f32x4 acc[8][2];
  #pragma unroll
  for (int i = 0; i < 8; i++) {
    acc[i][0] = (f32x4){0.f, 0.f, 0.f, 0.f};
    acc[i][1] = (f32x4){0.f, 0.f, 0.f, 0.f};
  }
  float m_run[2] = {-3.0e38f, -3.0e38f};
  float l_run[2] = {0.f, 0.f};

  const unsigned short* kbase = Kf + ((size_t)b * SEQ + cw * 16 + l15) * CD + l4 * 8;
  const unsigned short* vbase = VfT + ((size_t)b * CD + cw * 128 + l15) * SEQ + l4 * 8;

  for (int kv0 = 0; kv0 < SEQ; kv0 += 64) {
    // ---- QK^T (swapped: rows = kv, cols = q) ----
    f32x4 sf[2] = {(f32x4){0.f, 0.f, 0.f, 0.f}, (f32x4){0.f, 0.f, 0.f, 0.f}};
    const unsigned short* kt = kbase + (size_t)kv0 * CD;
    #pragma unroll 4
    for (int ck = 0; ck < CD; ck += 32) {
      bf16x8 ka = *(const bf16x8*)(kt + ck);
      #pragma unroll
      for (int jf = 0; jf < 2; jf++) {
        int qq = jq[jf];
        int off = qq * 1024 + (((ck + l4 * 8) * 2) ^ ((qq & 7) << 4));
        bf16x8 qv = *(const bf16x8*)((const char*)Qs + off);
        sf[jf] = MFMA16(ka, qv, sf[jf]);
      }
    }

    // ---- per-strip max ----
    #pragma unroll
    for (int jf = 0; jf < 2; jf++) {
      float mv = fmaxf(fmaxf(sf[jf][0], sf[jf][1]), fmaxf(sf[jf][2], sf[jf][3]));
      mv = fmaxf(mv, __shfl_xor(mv, 16, 64));
      mv = fmaxf(mv, __shfl_xor(mv, 32, 64));
      if (lane < 16) smx[qw][cw][jf * 16 + l15] = mv;
    }
    __syncthreads();

    float mnew[2], alpha[2];
    #pragma unroll
    for (int jf = 0; jf < 2; jf++) {
      int idx = jf * 16 + l15;
      float tm = fmaxf(fmaxf(smx[qw][0][idx], smx[qw][1][idx]),
                       fmaxf(smx[qw][2][idx], smx[qw][3][idx]));
      mnew[jf] = fmaxf(m_run[jf], tm);
      alpha[jf] = exp2f(m_run[jf] - mnew[jf]);
      float p0 = exp2f(sf[jf][0] - mnew[jf]);
      float p1 = exp2f(sf[jf][1] - mnew[jf]);
      float p2 = exp2f(sf[jf][2] - mnew[jf]);
      float p3 = exp2f(sf[jf][3] - mnew[jf]);
      ushort4 pk;
      pk.x = f2bf(p0); pk.y = f2bf(p1); pk.z = f2bf(p2); pk.w = f2bf(p3);
      int qq = jq[jf];
      int off = qq * 128 + (((cw * 16 + l4 * 4) * 2) ^ ((qq & 7) << 4));
      *(ushort4*)((char*)Ps + off) = pk;
      float ps = (p0 + p1) + (p2 + p3);
      ps += __shfl_xor(ps, 16, 64);
      ps += __shfl_xor(ps, 32, 64);
      if (lane < 16) ssm[qw][cw][idx] = ps;
    }
    __syncthreads();

    // ---- stats update + O rescale ----
    #pragma unroll
    for (int jf = 0; jf < 2; jf++) {
      int idx = jf * 16 + l15;
      float ls = (ssm[qw][0][idx] + ssm[qw][1][idx]) + (ssm[qw][2][idx] + ssm[qw][3][idx]);
      l_run[jf] = alpha[jf] * l_run[jf] + ls;
      m_run[jf] = mnew[jf];
    }
    #pragma unroll
    for (int i = 0; i < 8; i++) {
      acc[i][0] *= alpha[0];
      acc[i][1] *= alpha[1];
    }

    // ---- PV: O^T[c][q] += VfT x P^T ----
    #pragma unroll
    for (int kvs = 0; kvs < 64; kvs += 32) {
      bf16x8 pb[2];
      #pragma unroll
      for (int jf = 0; jf < 2; jf++) {
        int qq = jq[jf];
        int off = qq * 128 + ((((kvs + l4 * 8)) * 2) ^ ((qq & 7) << 4));
        pb[jf] = *(const bf16x8*)((const char*)Ps + off);
      }
      #pragma unroll
      for (int i = 0; i < 8; i++) {
        bf16x8 va = *(const bf16x8*)(vbase + (size_t)i * 16 * SEQ + kv0 + kvs);
        acc[i][0] = MFMA16(va, pb[0], acc[i][0]);
        acc[i][1] = MFMA16(va, pb[1], acc[i][1]);
      }
    }
  }

  // ---- epilogue: O / l, store bf16 Ao[b][s][c] ----
  float inv0 = 1.f / l_run[0], inv1 = 1.f / l_run[1];
  #pragma unroll
  for (int i = 0; i < 8; i++) {
    int c0 = cw * 128 + i * 16 + l4 * 4;
    ushort4 o4;
    o4.x = f2bf(acc[i][0][0] * inv0); o4.y = f2bf(acc[i][0][1] * inv0);
    o4.z = f2bf(acc[i][0][2] * inv0); o4.w = f2bf(acc[i][0][3] * inv0);
    *(ushort4*)&Ao[((size_t)b * SEQ + q0 + jq[0]) * CD + c0] = o4;
    o4.x = f2bf(acc[i][1][0] * inv1); o4.y = f2bf(acc[i][1][1] * inv1);
    o4.z = f2bf(acc[i][1][2] * inv1); o4.w = f2bf(acc[i][1][3] * inv1);
    *(ushort4*)&Ao[((size_t)b * SEQ + q0 + jq[1]) * CD + c0] = o4;
  }
}

// ---------------- output projection: out[b][o][s] fp32 ----------------
__global__ __launch_bounds__(256) void gemm_out(
    const unsigned short* __restrict__ W4, const float* __restrict__ b4,
    const unsigned short* __restrict__ Ao, float* __restrict__ out) {
  __shared__ unsigned short As[128 * 64], Bs[128 * 64];
  const int b = blockIdx.z;
  const int n0 = blockIdx.x * 128, m0 = blockIdx.y * 128;
  f32x4 acc[4][4];
  #pragma unroll
  for (int i = 0; i < 4; i++)
    #pragma unroll
    for (int j = 0; j < 4; j++) acc[i][j] = (f32x4){0.f, 0.f, 0.f, 0.f};
  gemm_core(W4 + ((size_t)3 * 512 + m0) * 512, Ao + ((size_t)b * SEQ + n0) * 512, As, Bs, acc);

  const int t = threadIdx.x;
  const int wid = t >> 6, lane = t & 63;
  const int l15 = lane & 15, l4 = lane >> 4;
  const int wr = wid >> 1, wc = wid & 1;
  #pragma unroll
  for (int i = 0; i < 4; i++) {
    int m = m0 + wr * 64 + i * 16 + l4 * 4;
    #pragma unroll
    for (int j = 0; j < 4; j++) {
      int n = n0 + wc * 64 + j * 16 + l15;
      #pragma unroll
      for (int r = 0; r < 4; r++)
        out[((size_t)b * CD + m + r) * SEQ + n] = acc[i][j][r] + b4[3 * 512 + m + r];
    }
  }
}

extern "C" void kernel_launch(void* const* d_in, const int* in_sizes, int n_in,
                              void* d_out, int out_size, void* d_ws, size_t ws_size,
                              hipStream_t stream) {
  (void)in_sizes; (void)n_in; (void)out_size; (void)ws_size;
  const float* q  = (const float*)d_in[0];
  const float* Wq = (const float*)d_in[1];
  const float* bq = (const float*)d_in[2];
  const float* Wk = (const float*)d_in[3];
  const float* bk = (const float*)d_in[4];
  const float* Wv = (const float*)d_in[5];
  const float* bv = (const float*)d_in[6];
  const float* Wo = (const float*)d_in[7];
  const float* bo = (const float*)d_in[8];
  float* out = (float*)d_out;

  char* ws = (char*)d_ws;
  unsigned short* qT  = (unsigned short*)(ws);                     // 16MB (reused as Ao)
  unsigned short* Qf  = (unsigned short*)(ws + ((size_t)16 << 20));
  unsigned short* Kf  = (unsigned short*)(ws + ((size_t)32 << 20));
  unsigned short* VfT = (unsigned short*)(ws + ((size_t)48 << 20));
  unsigned short* W4  = (unsigned short*)(ws + ((size_t)64 << 20)); // 2MB
  float* b4           = (float*)(ws + ((size_t)66 << 20));          // 8KB
  unsigned short* Ao = qT;

  convert_w<<<4096, 256, 0, stream>>>(Wq, Wk, Wv, Wo, bq, bk, bv, bo, W4, b4);
  transpose_q<<<dim3(128, 16, 4), 256, 0, stream>>>(q, qT);
  gemm_proj<<<dim3(4, 128, 3), 256, 0, stream>>>(qT, W4, b4, Qf, Kf, VfT);
  flash_attn<<<dim3(64, 4), 512, 0, stream>>>(Qf, Kf, VfT, Ao);
  gemm_out<<<dim3(32, 4, 4), 256, 0, stream>>>(W4, b4, Ao, out);
}

// Round 2
// 663.973 us; speedup vs baseline: 1.0801x; 1.0801x over previous
//
#include <hip/hip_runtime.h>

typedef short bf16x8 __attribute__((ext_vector_type(8)));
typedef float f32x4 __attribute__((ext_vector_type(4)));

#define MFMA16(a, b, c) __builtin_amdgcn_mfma_f32_16x16x32_bf16((a), (b), (c), 0, 0, 0)

#define SEQ 4096
#define CD 512

#define LGKM0 asm volatile("s_waitcnt lgkmcnt(0)" ::: "memory")
#define VM0   asm volatile("s_waitcnt vmcnt(0)" ::: "memory")

__device__ __forceinline__ unsigned short f2bf(float f) {
  unsigned u = __builtin_bit_cast(unsigned, f);
  u = u + 0x7FFFu + ((u >> 16) & 1u);
  return (unsigned short)(u >> 16);
}

__device__ __forceinline__ void gload_lds16(const void* g, void* l) {
  __builtin_amdgcn_global_load_lds(
      (const __attribute__((address_space(1))) void*)g,
      (__attribute__((address_space(3))) void*)l, 16, 0, 0);
}

// ---------------- weight convert (fp32 -> bf16, fold softmax scale into Wq/bq) ----------------
__global__ __launch_bounds__(256) void convert_w(
    const float* __restrict__ Wq, const float* __restrict__ Wk,
    const float* __restrict__ Wv, const float* __restrict__ Wo,
    const float* __restrict__ bq, const float* __restrict__ bk,
    const float* __restrict__ bv, const float* __restrict__ bo,
    unsigned short* __restrict__ W4, float* __restrict__ b4) {
  int i = blockIdx.x * 256 + threadIdx.x;            // 4*512*512 total
  int p = i >> 18, idx = i & 262143;
  const float sc = 1.4426950408889634f * 0.04419417382415922f;  // log2(e) * 512^-0.5
  const float* W = (p == 0) ? Wq : (p == 1) ? Wk : (p == 2) ? Wv : Wo;
  float v = W[idx] * ((p == 0) ? sc : 1.0f);
  W4[i] = f2bf(v);
  if (idx < 512) {
    const float* bb = (p == 0) ? bq : (p == 1) ? bk : (p == 2) ? bv : bo;
    b4[(p << 9) + idx] = bb[idx] * ((p == 0) ? sc : 1.0f);
  }
}

// ---------------- transpose q: fp32 [b][c][s] -> bf16 qT [b][s][c] ----------------
__global__ __launch_bounds__(256) void transpose_q(
    const float* __restrict__ q, unsigned short* __restrict__ qT) {
  __shared__ float tile[32][33];
  const int b = blockIdx.z, c0 = blockIdx.y * 32, s0 = blockIdx.x * 32;
  const int tx = threadIdx.x & 31, ty = threadIdx.x >> 5;
  #pragma unroll
  for (int i = 0; i < 4; i++) {
    int c = ty + i * 8;
    tile[c][tx] = q[((size_t)b * CD + c0 + c) * SEQ + s0 + tx];
  }
  __syncthreads();
  #pragma unroll
  for (int i = 0; i < 4; i++) {
    int s = ty + i * 8;
    qT[((size_t)b * SEQ + s0 + s) * CD + c0 + tx] = f2bf(tile[tx][s]);
  }
}

// ---------------- shared BT-GEMM core: 128x128 tile, BK=64, 4 waves ----------------
__device__ __forceinline__ void gemm_core(
    const unsigned short* __restrict__ Ap, const unsigned short* __restrict__ Bp,
    unsigned short* As, unsigned short* Bs, f32x4 acc[4][4]) {
  const int t = threadIdx.x;
  const int wid = t >> 6, lane = t & 63;
  const int l15 = lane & 15, l4 = lane >> 4;
  const int wr = wid >> 1, wc = wid & 1;
  for (int k0 = 0; k0 < 512; k0 += 64) {
    #pragma unroll
    for (int j = 0; j < 4; j++) {
      int slot = j * 256 + t;
      int row = slot >> 3, kc = slot & 7;
      int kcs = kc ^ (row & 7);
      gload_lds16(Ap + (size_t)row * 512 + k0 + kcs * 8, As + (j * 256 + wid * 64) * 8);
      gload_lds16(Bp + (size_t)row * 512 + k0 + kcs * 8, Bs + (j * 256 + wid * 64) * 8);
    }
    __syncthreads();
    #pragma unroll
    for (int ks = 0; ks < 2; ks++) {
      bf16x8 af[4], bf[4];
      #pragma unroll
      for (int i = 0; i < 4; i++) {
        int ra = wr * 64 + i * 16 + l15;
        af[i] = *(const bf16x8*)(As + ra * 64 + (((ks << 2) | l4) ^ (ra & 7)) * 8);
        int rb = wc * 64 + i * 16 + l15;
        bf[i] = *(const bf16x8*)(Bs + rb * 64 + (((ks << 2) | l4) ^ (rb & 7)) * 8);
      }
      #pragma unroll
      for (int i = 0; i < 4; i++)
        #pragma unroll
        for (int j = 0; j < 4; j++)
          acc[i][j] = MFMA16(af[i], bf[j], acc[i][j]);
    }
    __syncthreads();
  }
}

// ---------------- QKV projection: z = 0(Q),1(K),2(V transposed) ----------------
__global__ __launch_bounds__(256) void gemm_proj(
    const unsigned short* __restrict__ qT, const unsigned short* __restrict__ W4,
    const float* __restrict__ b4,
    unsigned short* __restrict__ Qf, unsigned short* __restrict__ Kf,
    unsigned short* __restrict__ VfT) {
  __shared__ unsigned short As[128 * 64], Bs[128 * 64];
  const int p = blockIdx.z;
  const int n0 = blockIdx.x * 128, m0 = blockIdx.y * 128;
  f32x4 acc[4][4];
  #pragma unroll
  for (int i = 0; i < 4; i++)
    #pragma unroll
    for (int j = 0; j < 4; j++) acc[i][j] = (f32x4){0.f, 0.f, 0.f, 0.f};
  gemm_core(qT + (size_t)m0 * 512, W4 + ((size_t)p * 512 + n0) * 512, As, Bs, acc);

  const int t = threadIdx.x;
  const int wid = t >> 6, lane = t & 63;
  const int l15 = lane & 15, l4 = lane >> 4;
  const int wr = wid >> 1, wc = wid & 1;

  if (p < 2) {
    unsigned short* out = (p == 0) ? Qf : Kf;
    #pragma unroll
    for (int j = 0; j < 4; j++) {
      int n = n0 + wc * 64 + j * 16 + l15;
      float bias = b4[p * 512 + n];
      #pragma unroll
      for (int i = 0; i < 4; i++) {
        int m = m0 + wr * 64 + i * 16 + l4 * 4;
        #pragma unroll
        for (int r = 0; r < 4; r++)
          out[(size_t)(m + r) * 512 + n] = f2bf(acc[i][j][r] + bias);
      }
    }
  } else {
    int bb = m0 >> 12, sb = m0 & 4095;
    #pragma unroll
    for (int j = 0; j < 4; j++) {
      int n = n0 + wc * 64 + j * 16 + l15;
      float bias = b4[2 * 512 + n];
      #pragma unroll
      for (int i = 0; i < 4; i++) {
        int s = sb + wr * 64 + i * 16 + l4 * 4;
        ushort4 v;
        v.x = f2bf(acc[i][j][0] + bias);
        v.y = f2bf(acc[i][j][1] + bias);
        v.z = f2bf(acc[i][j][2] + bias);
        v.w = f2bf(acc[i][j][3] + bias);
        *(ushort4*)&VfT[((size_t)bb * CD + n) * SEQ + s] = v;
      }
    }
  }
}

// ---------------- flash attention: QBLK=64, KVBLK=64, 8 waves ----------------
// K/V register double-buffer prefetch; raw barriers (no vmcnt drain); XCD batch affinity.
__global__ __launch_bounds__(512, 2) void flash_attn(
    const unsigned short* __restrict__ Qf, const unsigned short* __restrict__ Kf,
    const unsigned short* __restrict__ VfT, unsigned short* __restrict__ Ao) {
  __shared__ unsigned short Qs[64 * 512];   // 64KB, chunk-swizzled
  __shared__ unsigned short Ps[64 * 64];    // 8KB, [q][kv], byte-swizzled
  __shared__ float smx[2][4][32];
  __shared__ float ssm[2][4][32];

  const int t = threadIdx.x;
  const int wid = t >> 6, lane = t & 63;
  const int cw = wid & 3, qw = wid >> 2;
  const int l15 = lane & 15, l4 = lane >> 4;

  // XCD-batch affinity: xcd = id&7 owns batch xcd>>1; q-tiles split across the XCD pair.
  const int id = blockIdx.x;
  const int xcd = id & 7;
  const int b = xcd >> 1;
  const int q0 = ((id >> 3) + ((xcd & 1) << 5)) * 64;

  {  // stage Q tile (64 x 512) into LDS, source-chunk swizzled
    const unsigned short* qb = Qf + ((size_t)b * SEQ + q0) * CD;
    #pragma unroll
    for (int i = 0; i < 8; i++) {
      int slot = i * 512 + t;
      int row = slot >> 6, kc = slot & 63;
      int kcs = kc ^ (row & 7);
      gload_lds16(qb + (size_t)row * CD + kcs * 8, Qs + (size_t)(i * 512 + wid * 64) * 8);
    }
  }

  const unsigned short* kbase = Kf + ((size_t)b * SEQ + cw * 16 + l15) * CD + l4 * 8;
  const unsigned short* vbase = VfT + ((size_t)b * CD + cw * 128 + l15) * SEQ + l4 * 8;

  // prologue register prefetch of K(0), V(0)
  bf16x8 kreg[16], vreg[16];
  #pragma unroll
  for (int ck = 0; ck < 16; ck++) kreg[ck] = *(const bf16x8*)(kbase + ck * 32);
  #pragma unroll
  for (int i = 0; i < 8; i++) {
    vreg[i * 2 + 0] = *(const bf16x8*)(vbase + (size_t)i * 16 * SEQ);
    vreg[i * 2 + 1] = *(const bf16x8*)(vbase + (size_t)i * 16 * SEQ + 32);
  }

  VM0;                               // Q (gload_lds) visible to all waves
  __builtin_amdgcn_s_barrier();

  const int jq[2] = {qw * 32 + l15, qw * 32 + 16 + l15};
  f32x4 acc[8][2];
  #pragma unroll
  for (int i = 0; i < 8; i++) {
    acc[i][0] = (f32x4){0.f, 0.f, 0.f, 0.f};
    acc[i][1] = (f32x4){0.f, 0.f, 0.f, 0.f};
  }
  float m_run[2] = {-3.0e38f, -3.0e38f};
  float l_run[2] = {0.f, 0.f};

  for (int kv0 = 0; kv0 < SEQ; kv0 += 64) {
    const int kvn = (kv0 + 64 < SEQ) ? kv0 + 64 : kv0;  // clamped next tile

    // ---- QK^T (swapped: rows = kv, cols = q), K from registers ----
    f32x4 sf[2] = {(f32x4){0.f, 0.f, 0.f, 0.f}, (f32x4){0.f, 0.f, 0.f, 0.f}};
    #pragma unroll
    for (int ck = 0; ck < 16; ck++) {
      bf16x8 ka = kreg[ck];
      #pragma unroll
      for (int jf = 0; jf < 2; jf++) {
        int qq = jq[jf];
        int off = qq * 1024 + (((ck * 32 + l4 * 8) * 2) ^ ((qq & 7) << 4));
        bf16x8 qv = *(const bf16x8*)((const char*)Qs + off);
        sf[jf] = MFMA16(ka, qv, sf[jf]);
      }
    }

    // ---- prefetch K(t+1) into registers (lands during softmax+PV) ----
    {
      const unsigned short* kn = kbase + (size_t)kvn * CD;
      #pragma unroll
      for (int ck = 0; ck < 16; ck++) kreg[ck] = *(const bf16x8*)(kn + ck * 32);
    }

    // ---- per-strip max ----
    #pragma unroll
    for (int jf = 0; jf < 2; jf++) {
      float mv = fmaxf(fmaxf(sf[jf][0], sf[jf][1]), fmaxf(sf[jf][2], sf[jf][3]));
      mv = fmaxf(mv, __shfl_xor(mv, 16, 64));
      mv = fmaxf(mv, __shfl_xor(mv, 32, 64));
      if (lane < 16) smx[qw][cw][jf * 16 + l15] = mv;
    }
    LGKM0;
    __builtin_amdgcn_s_barrier();    // B1 (no vmcnt drain: K prefetch stays in flight)

    float mnew[2], alpha[2];
    #pragma unroll
    for (int jf = 0; jf < 2; jf++) {
      int idx = jf * 16 + l15;
      float tm = fmaxf(fmaxf(smx[qw][0][idx], smx[qw][1][idx]),
                       fmaxf(smx[qw][2][idx], smx[qw][3][idx]));
      mnew[jf] = fmaxf(m_run[jf], tm);
      alpha[jf] = exp2f(m_run[jf] - mnew[jf]);
      float p0 = exp2f(sf[jf][0] - mnew[jf]);
      float p1 = exp2f(sf[jf][1] - mnew[jf]);
      float p2 = exp2f(sf[jf][2] - mnew[jf]);
      float p3 = exp2f(sf[jf][3] - mnew[jf]);
      ushort4 pk;
      pk.x = f2bf(p0); pk.y = f2bf(p1); pk.z = f2bf(p2); pk.w = f2bf(p3);
      int qq = jq[jf];
      int off = qq * 128 + (((cw * 16 + l4 * 4) * 2) ^ ((qq & 7) << 4));
      *(ushort4*)((char*)Ps + off) = pk;
      float ps = (p0 + p1) + (p2 + p3);
      ps += __shfl_xor(ps, 16, 64);
      ps += __shfl_xor(ps, 32, 64);
      if (lane < 16) ssm[qw][cw][idx] = ps;
    }
    LGKM0;
    __builtin_amdgcn_s_barrier();    // B2

    // ---- stats update + O rescale ----
    #pragma unroll
    for (int jf = 0; jf < 2; jf++) {
      int idx = jf * 16 + l15;
      float ls = (ssm[qw][0][idx] + ssm[qw][1][idx]) + (ssm[qw][2][idx] + ssm[qw][3][idx]);
      l_run[jf] = alpha[jf] * l_run[jf] + ls;
      m_run[jf] = mnew[jf];
    }
    #pragma unroll
    for (int i = 0; i < 8; i++) {
      acc[i][0] *= alpha[0];
      acc[i][1] *= alpha[1];
    }

    // ---- PV: O^T[c][q] += VfT x P^T, V from registers ----
    #pragma unroll
    for (int kvs = 0; kvs < 2; kvs++) {
      bf16x8 pb[2];
      #pragma unroll
      for (int jf = 0; jf < 2; jf++) {
        int qq = jq[jf];
        int off = qq * 128 + (((kvs * 32 + l4 * 8) * 2) ^ ((qq & 7) << 4));
        pb[jf] = *(const bf16x8*)((const char*)Ps + off);
      }
      #pragma unroll
      for (int i = 0; i < 8; i++) {
        acc[i][0] = MFMA16(vreg[i * 2 + kvs], pb[0], acc[i][0]);
        acc[i][1] = MFMA16(vreg[i * 2 + kvs], pb[1], acc[i][1]);
      }
    }

    // ---- prefetch V(t+1) into registers (lands during next QK+softmax) ----
    {
      const unsigned short* vn = vbase + kvn;
      #pragma unroll
      for (int i = 0; i < 8; i++) {
        vreg[i * 2 + 0] = *(const bf16x8*)(vn + (size_t)i * 16 * SEQ);
        vreg[i * 2 + 1] = *(const bf16x8*)(vn + (size_t)i * 16 * SEQ + 32);
      }
    }
  }

  // ---- epilogue: O / l, store bf16 Ao[b][s][c] ----
  float inv0 = 1.f / l_run[0], inv1 = 1.f / l_run[1];
  #pragma unroll
  for (int i = 0; i < 8; i++) {
    int c0 = cw * 128 + i * 16 + l4 * 4;
    ushort4 o4;
    o4.x = f2bf(acc[i][0][0] * inv0); o4.y = f2bf(acc[i][0][1] * inv0);
    o4.z = f2bf(acc[i][0][2] * inv0); o4.w = f2bf(acc[i][0][3] * inv0);
    *(ushort4*)&Ao[((size_t)b * SEQ + q0 + jq[0]) * CD + c0] = o4;
    o4.x = f2bf(acc[i][1][0] * inv1); o4.y = f2bf(acc[i][1][1] * inv1);
    o4.z = f2bf(acc[i][1][2] * inv1); o4.w = f2bf(acc[i][1][3] * inv1);
    *(ushort4*)&Ao[((size_t)b * SEQ + q0 + jq[1]) * CD + c0] = o4;
  }
}

// ---------------- output projection: out[b][o][s] fp32 ----------------
__global__ __launch_bounds__(256) void gemm_out(
    const unsigned short* __restrict__ W4, const float* __restrict__ b4,
    const unsigned short* __restrict__ Ao, float* __restrict__ out) {
  __shared__ unsigned short As[128 * 64], Bs[128 * 64];
  const int b = blockIdx.z;
  const int n0 = blockIdx.x * 128, m0 = blockIdx.y * 128;
  f32x4 acc[4][4];
  #pragma unroll
  for (int i = 0; i < 4; i++)
    #pragma unroll
    for (int j = 0; j < 4; j++) acc[i][j] = (f32x4){0.f, 0.f, 0.f, 0.f};
  gemm_core(W4 + ((size_t)3 * 512 + m0) * 512, Ao + ((size_t)b * SEQ + n0) * 512, As, Bs, acc);

  const int t = threadIdx.x;
  const int wid = t >> 6, lane = t & 63;
  const int l15 = lane & 15, l4 = lane >> 4;
  const int wr = wid >> 1, wc = wid & 1;
  #pragma unroll
  for (int i = 0; i < 4; i++) {
    int m = m0 + wr * 64 + i * 16 + l4 * 4;
    #pragma unroll
    for (int j = 0; j < 4; j++) {
      int n = n0 + wc * 64 + j * 16 + l15;
      #pragma unroll
      for (int r = 0; r < 4; r++)
        out[((size_t)b * CD + m + r) * SEQ + n] = acc[i][j][r] + b4[3 * 512 + m + r];
    }
  }
}

extern "C" void kernel_launch(void* const* d_in, const int* in_sizes, int n_in,
                              void* d_out, int out_size, void* d_ws, size_t ws_size,
                              hipStream_t stream) {
  (void)in_sizes; (void)n_in; (void)out_size; (void)ws_size;
  const float* q  = (const float*)d_in[0];
  const float* Wq = (const float*)d_in[1];
  const float* bq = (const float*)d_in[2];
  const float* Wk = (const float*)d_in[3];
  const float* bk = (const float*)d_in[4];
  const float* Wv = (const float*)d_in[5];
  const float* bv = (const float*)d_in[6];
  const float* Wo = (const float*)d_in[7];
  const float* bo = (const float*)d_in[8];
  float* out = (float*)d_out;

  char* ws = (char*)d_ws;
  unsigned short* qT  = (unsigned short*)(ws);                     // 16MB (reused as Ao)
  unsigned short* Qf  = (unsigned short*)(ws + ((size_t)16 << 20));
  unsigned short* Kf  = (unsigned short*)(ws + ((size_t)32 << 20));
  unsigned short* VfT = (unsigned short*)(ws + ((size_t)48 << 20));
  unsigned short* W4  = (unsigned short*)(ws + ((size_t)64 << 20)); // 2MB
  float* b4           = (float*)(ws + ((size_t)66 << 20));          // 8KB
  unsigned short* Ao = qT;

  convert_w<<<4096, 256, 0, stream>>>(Wq, Wk, Wv, Wo, bq, bk, bv, bo, W4, b4);
  transpose_q<<<dim3(128, 16, 4), 256, 0, stream>>>(q, qT);
  gemm_proj<<<dim3(4, 128, 3), 256, 0, stream>>>(qT, W4, b4, Qf, Kf, VfT);
  flash_attn<<<256, 512, 0, stream>>>(Qf, Kf, VfT, Ao);
  gemm_out<<<dim3(32, 4, 4), 256, 0, stream>>>(W4, b4, Ao, out);
}